// Round 1
// baseline (700.487 us; speedup 1.0000x reference)
//
#include <hip/hip_runtime.h>
#include <math.h>

// ---------------------------------------------------------------------------
// 2-layer GCN:  out = GCNConv(relu(GCNConv(x, W1, b1)), W2, b2)
// Factorization: g = (x@W) * dinv[row];  agg[d] = g[d] + sum_{s in in(d)} g[s];
//                out[d] = agg[d]*dinv[d] + b   (dinv = rsqrt(indeg+1))
// CSR built on-device each call (ws is re-poisoned): histogram -> 3-pass
// exclusive scan -> bucket fill. No float atomics anywhere.
// ---------------------------------------------------------------------------

__global__ __launch_bounds__(256) void zero_counts(int* __restrict__ cnt,
                                                   int* __restrict__ cur, int n) {
    int i = blockIdx.x * 256 + threadIdx.x;
    if (i < n) { cnt[i] = 0; cur[i] = 0; }
}

__global__ __launch_bounds__(256) void hist_kernel(const int* __restrict__ dst,
                                                   int* __restrict__ cnt, int E, int N) {
    int i = blockIdx.x * 256 + threadIdx.x;
    if (i < E) {
        int d = dst[i];
        if ((unsigned)d < (unsigned)N) atomicAdd(&cnt[d], 1);
    }
}

__global__ __launch_bounds__(256) void dinv_kernel(const int* __restrict__ cnt,
                                                   float* __restrict__ dinv, int N) {
    int i = blockIdx.x * 256 + threadIdx.x;
    if (i < N) dinv[i] = rsqrtf((float)(cnt[i] + 1));  // deg includes self-loop, >= 1
}

__global__ __launch_bounds__(256) void block_sums(const int* __restrict__ cnt,
                                                  int* __restrict__ bsums, int N) {
    __shared__ int sh[256];
    int t = threadIdx.x;
    int i = blockIdx.x * 256 + t;
    sh[t] = (i < N) ? cnt[i] : 0;
    __syncthreads();
    for (int s = 128; s > 0; s >>= 1) {
        if (t < s) sh[t] += sh[t + s];
        __syncthreads();
    }
    if (t == 0) bsums[blockIdx.x] = sh[0];
}

__global__ __launch_bounds__(512) void scan_blocksums(int* __restrict__ bsums, int nb) {
    __shared__ int sh[512];
    int t = threadIdx.x;
    int orig = (t < nb) ? bsums[t] : 0;
    sh[t] = orig;
    __syncthreads();
    for (int d = 1; d < 512; d <<= 1) {
        int v = (t >= d) ? sh[t - d] : 0;
        __syncthreads();
        sh[t] += v;
        __syncthreads();
    }
    if (t < nb) bsums[t] = sh[t] - orig;  // exclusive
}

__global__ __launch_bounds__(256) void scan_chunks(const int* __restrict__ cnt,
                                                   const int* __restrict__ bsums,
                                                   int* __restrict__ offs, int N) {
    __shared__ int sh[256];
    int t = threadIdx.x;
    int i = blockIdx.x * 256 + t;
    int orig = (i < N) ? cnt[i] : 0;
    sh[t] = orig;
    __syncthreads();
    for (int d = 1; d < 256; d <<= 1) {
        int v = (t >= d) ? sh[t - d] : 0;
        __syncthreads();
        sh[t] += v;
        __syncthreads();
    }
    if (i < N) offs[i] = bsums[blockIdx.x] + sh[t] - orig;  // exclusive
}

__global__ __launch_bounds__(256) void csr_fill(const int* __restrict__ src,
                                                const int* __restrict__ dst,
                                                const int* __restrict__ offs,
                                                int* __restrict__ cur,
                                                int* __restrict__ csr, int E, int N) {
    int i = blockIdx.x * 256 + threadIdx.x;
    if (i >= E) return;
    int d = dst[i];
    if ((unsigned)d >= (unsigned)N) return;
    int p = offs[d] + atomicAdd(&cur[d], 1);
    csr[p] = src[i];
}

// G[row] = (X[row] @ W) * dinv[row].  X:[N,K], W:[K,64], G:[N,64].
// Block: 32 rows x 64 cols. Thread (cg=t&15 -> 4 cols, ry=t>>4 -> rows ry, ry+16).
// Xs padded to K+1 (odd stride): rows ry / ry+16 land in different banks.
template <int K>
__global__ __launch_bounds__(256) void gemm_scale(const float* __restrict__ X,
                                                  const float* __restrict__ W,
                                                  const float* __restrict__ dinv,
                                                  float* __restrict__ G, int N) {
    __shared__ float Ws[K * 64];
    __shared__ float Xs[32][K + 1];
    const int t  = threadIdx.x;
    const int r0 = blockIdx.x * 32;

    for (int i = t; i < K * 16; i += 256)              // K*64/4 float4s
        ((float4*)Ws)[i] = ((const float4*)W)[i];

    for (int i = t; i < 32 * (K / 4); i += 256) {
        int row = i / (K / 4);
        int kk  = (i % (K / 4)) * 4;
        int gr  = r0 + row;
        float4 v = make_float4(0.f, 0.f, 0.f, 0.f);
        if (gr < N) v = *(const float4*)(X + (size_t)gr * K + kk);
        Xs[row][kk + 0] = v.x; Xs[row][kk + 1] = v.y;
        Xs[row][kk + 2] = v.z; Xs[row][kk + 3] = v.w;
    }
    __syncthreads();

    const int cg = (t & 15) * 4;
    const int ry = t >> 4;  // 0..15
    float4 a0 = make_float4(0.f, 0.f, 0.f, 0.f);
    float4 a1 = make_float4(0.f, 0.f, 0.f, 0.f);
#pragma unroll 8
    for (int k = 0; k < K; ++k) {
        float4 w = *(const float4*)&Ws[k * 64 + cg];
        float x0 = Xs[ry][k];
        float x1 = Xs[ry + 16][k];
        a0.x = fmaf(x0, w.x, a0.x); a0.y = fmaf(x0, w.y, a0.y);
        a0.z = fmaf(x0, w.z, a0.z); a0.w = fmaf(x0, w.w, a0.w);
        a1.x = fmaf(x1, w.x, a1.x); a1.y = fmaf(x1, w.y, a1.y);
        a1.z = fmaf(x1, w.z, a1.z); a1.w = fmaf(x1, w.w, a1.w);
    }

    int row0 = r0 + ry;
    if (row0 < N) {
        float s = dinv[row0];
        float4 o = make_float4(a0.x * s, a0.y * s, a0.z * s, a0.w * s);
        *(float4*)(G + (size_t)row0 * 64 + cg) = o;
    }
    int row1 = r0 + ry + 16;
    if (row1 < N) {
        float s = dinv[row1];
        float4 o = make_float4(a1.x * s, a1.y * s, a1.z * s, a1.w * s);
        *(float4*)(G + (size_t)row1 * 64 + cg) = o;
    }
}

// One wave per node, lane = feature column (64 cols exactly). Coalesced 256B
// gathers of G rows; unroll-4 for memory-level parallelism.
__global__ __launch_bounds__(256) void aggregate(const float* __restrict__ G,
                                                 const int* __restrict__ offs,
                                                 const int* __restrict__ cnt,
                                                 const int* __restrict__ csr,
                                                 const float* __restrict__ dinv,
                                                 const float* __restrict__ bias,
                                                 float* __restrict__ out, int N,
                                                 int do_relu) {
    int w    = (blockIdx.x * 256 + threadIdx.x) >> 6;
    int lane = threadIdx.x & 63;
    if (w >= N) return;
    int beg = offs[w];
    int num = cnt[w];
    float acc = G[(size_t)w * 64 + lane];  // self-loop term
    int e = 0;
    for (; e + 4 <= num; e += 4) {
        int s0 = csr[beg + e + 0];
        int s1 = csr[beg + e + 1];
        int s2 = csr[beg + e + 2];
        int s3 = csr[beg + e + 3];
        float g0 = G[(size_t)s0 * 64 + lane];
        float g1 = G[(size_t)s1 * 64 + lane];
        float g2 = G[(size_t)s2 * 64 + lane];
        float g3 = G[(size_t)s3 * 64 + lane];
        acc += g0; acc += g1; acc += g2; acc += g3;
    }
    for (; e < num; ++e) acc += G[(size_t)csr[beg + e] * 64 + lane];
    float v = fmaf(acc, dinv[w], bias[lane]);
    if (do_relu) v = fmaxf(v, 0.f);
    out[(size_t)w * 64 + lane] = v;
}

extern "C" void kernel_launch(void* const* d_in, const int* in_sizes, int n_in,
                              void* d_out, int out_size, void* d_ws, size_t ws_size,
                              hipStream_t stream) {
    const float* x  = (const float*)d_in[0];
    const int*   ei = (const int*)d_in[1];
    const float* W1 = (const float*)d_in[2];
    const float* b1 = (const float*)d_in[3];
    const float* W2 = (const float*)d_in[4];
    const float* b2 = (const float*)d_in[5];
    float* out = (float*)d_out;

    const int IN_CH = 128;
    const int N = in_sizes[0] / IN_CH;   // 100000
    const int E = in_sizes[1] / 2;       // 3200000
    const int* src = ei;
    const int* dst = ei + E;

    // workspace carve-up (~65.4 MB total)
    char* ws = (char*)d_ws;
    size_t off = 0;
    auto take = [&](size_t bytes) -> char* {
        char* p = ws + off;
        off += (bytes + 255) & ~(size_t)255;
        return p;
    };
    int*   cnt   = (int*)take((size_t)N * 4);
    int*   cur   = (int*)take((size_t)N * 4);
    int*   offs  = (int*)take((size_t)N * 4);
    float* dinv  = (float*)take((size_t)N * 4);
    int*   bsums = (int*)take(512 * 4);
    int*   csr   = (int*)take((size_t)E * 4);
    float* g     = (float*)take((size_t)N * 64 * 4);
    float* a1    = (float*)take((size_t)N * 64 * 4);

    const int nbN = (N + 255) / 256;     // 391 (<=512 for scan_blocksums)
    const int nbE = (E + 255) / 256;

    zero_counts<<<nbN, 256, 0, stream>>>(cnt, cur, N);
    hist_kernel<<<nbE, 256, 0, stream>>>(dst, cnt, E, N);
    dinv_kernel<<<nbN, 256, 0, stream>>>(cnt, dinv, N);
    block_sums<<<nbN, 256, 0, stream>>>(cnt, bsums, N);
    scan_blocksums<<<1, 512, 0, stream>>>(bsums, nbN);
    scan_chunks<<<nbN, 256, 0, stream>>>(cnt, bsums, offs, N);
    csr_fill<<<nbE, 256, 0, stream>>>(src, dst, offs, cur, csr, E, N);

    // layer 1
    gemm_scale<128><<<(N + 31) / 32, 256, 0, stream>>>(x, W1, dinv, g, N);
    aggregate<<<(N + 3) / 4, 256, 0, stream>>>(g, offs, cnt, csr, dinv, b1, a1, N, 1);
    // layer 2
    gemm_scale<64><<<(N + 31) / 32, 256, 0, stream>>>(a1, W2, dinv, g, N);
    aggregate<<<(N + 3) / 4, 256, 0, stream>>>(g, offs, cnt, csr, dinv, b2, out, N, 0);
}

// Round 2
// 606.307 us; speedup vs baseline: 1.1553x; 1.1553x over previous
//
#include <hip/hip_runtime.h>
#include <math.h>

// ---------------------------------------------------------------------------
// 2-layer GCN:  out = GCNConv(relu(GCNConv(x, W1, b1)), W2, b2)
// Factorization: g = (x@W) * dinv[row];  agg[d] = g[d] + sum_{s in in(d)} g[s];
//                out[d] = agg[d]*dinv[d] + b   (dinv = rsqrt(indeg+1))
//
// CSR built on-device each call. R1 lesson: naive per-node scatter (csr_fill)
// produced 197MB of partial-line HBM writebacks (~16x amplification, 215us).
// R2: two-phase bucketed counting sort, all global writes are contiguous
// full-line runs:
//   Phase A (bucket_bin): LDS-staged binning into 196 buckets of 512 nodes.
//   Phase B (csr_sort):   per-bucket fine sort fully in LDS, coalesced out.
// ---------------------------------------------------------------------------

#define BKT_SHIFT 9               // 512 nodes per bucket
#define BKT_NODES 512
#define NBSH      256             // LDS array size >= bucket count (196)
#define CHUNK     8192            // edges per bucket_bin block
#define MAXB      20480           // max edges per bucket in csr_sort LDS path

__global__ __launch_bounds__(256) void zero_counts(int* __restrict__ cnt,
                                                   int* __restrict__ bcur, int n) {
    int i = blockIdx.x * 256 + threadIdx.x;
    if (i < n) cnt[i] = 0;
    if (i < NBSH) bcur[i] = 0;
}

__global__ __launch_bounds__(256) void hist_kernel(const int* __restrict__ dst,
                                                   int* __restrict__ cnt, int E, int N) {
    int i = blockIdx.x * 256 + threadIdx.x;
    if (i < E) {
        int d = dst[i];
        if ((unsigned)d < (unsigned)N) atomicAdd(&cnt[d], 1);
    }
}

__global__ __launch_bounds__(256) void dinv_kernel(const int* __restrict__ cnt,
                                                   float* __restrict__ dinv, int N) {
    int i = blockIdx.x * 256 + threadIdx.x;
    if (i < N) dinv[i] = rsqrtf((float)(cnt[i] + 1));  // deg includes self-loop
}

__global__ __launch_bounds__(256) void block_sums(const int* __restrict__ cnt,
                                                  int* __restrict__ bsums, int N) {
    __shared__ int sh[256];
    int t = threadIdx.x;
    int i = blockIdx.x * 256 + t;
    sh[t] = (i < N) ? cnt[i] : 0;
    __syncthreads();
    for (int s = 128; s > 0; s >>= 1) {
        if (t < s) sh[t] += sh[t + s];
        __syncthreads();
    }
    if (t == 0) bsums[blockIdx.x] = sh[0];
}

__global__ __launch_bounds__(512) void scan_blocksums(int* __restrict__ bsums, int nb) {
    __shared__ int sh[512];
    int t = threadIdx.x;
    int orig = (t < nb) ? bsums[t] : 0;
    sh[t] = orig;
    __syncthreads();
    for (int d = 1; d < 512; d <<= 1) {
        int v = (t >= d) ? sh[t - d] : 0;
        __syncthreads();
        sh[t] += v;
        __syncthreads();
    }
    if (t < nb) bsums[t] = sh[t] - orig;  // exclusive
}

__global__ __launch_bounds__(256) void scan_chunks(const int* __restrict__ cnt,
                                                   const int* __restrict__ bsums,
                                                   int* __restrict__ offs, int N) {
    __shared__ int sh[256];
    int t = threadIdx.x;
    int i = blockIdx.x * 256 + t;
    int orig = (i < N) ? cnt[i] : 0;
    sh[t] = orig;
    __syncthreads();
    for (int d = 1; d < 256; d <<= 1) {
        int v = (t >= d) ? sh[t - d] : 0;
        __syncthreads();
        sh[t] += v;
        __syncthreads();
    }
    if (i < N) offs[i] = bsums[blockIdx.x] + sh[t] - orig;  // exclusive
}

// Phase A: bin edges into buckets of 512 nodes. Packed pair: (dst&511)<<17|src
// (src < 2^17 since N = 100000). All global writes are contiguous per-bucket
// runs (~42 x 4B avg) from LDS staging — near-full-line.
__global__ __launch_bounds__(256) void bucket_bin(const int* __restrict__ src,
                                                  const int* __restrict__ dst,
                                                  const int* __restrict__ offs,
                                                  int* __restrict__ bcur,
                                                  unsigned* __restrict__ pairs,
                                                  int E, int N, int NB) {
    __shared__ unsigned stag[CHUNK];   // 32KB
    __shared__ int hist[NBSH];
    __shared__ int lofs[NBSH];         // inclusive scan
    __shared__ int lcur[NBSH];
    __shared__ int gbase[NBSH];
    const int t  = threadIdx.x;
    const int e0 = blockIdx.x * CHUNK;
    const int n  = min(CHUNK, E - e0);

    for (int i = t; i < NBSH; i += 256) hist[i] = 0;
    __syncthreads();
    for (int i = t; i < n; i += 256) {
        int d = dst[e0 + i];
        atomicAdd(&hist[d >> BKT_SHIFT], 1);
    }
    __syncthreads();
    // Hillis-Steele inclusive scan over 256 entries
    int v = hist[t];
    lofs[t] = v;
    __syncthreads();
    for (int d = 1; d < 256; d <<= 1) {
        int u = (t >= d) ? lofs[t - d] : 0;
        __syncthreads();
        lofs[t] += u;
        __syncthreads();
    }
    if (t < NB) {
        lcur[t]  = lofs[t] - v;  // exclusive local offset
        gbase[t] = (v > 0) ? offs[t << BKT_SHIFT] + atomicAdd(&bcur[t], v) : 0;
    }
    __syncthreads();
    // scatter into LDS staging (bucket-contiguous)
    for (int i = t; i < n; i += 256) {
        int d = dst[e0 + i];
        int s = src[e0 + i];
        int b = d >> BKT_SHIFT;
        int p = atomicAdd(&lcur[b], 1);
        stag[p] = ((unsigned)(d & (BKT_NODES - 1)) << 17) | (unsigned)s;
    }
    __syncthreads();
    // coalesced per-bucket run copy-out
    for (int b = 0; b < NB; ++b) {
        int cb = hist[b];
        if (cb == 0) continue;
        int lo = lofs[b] - cb;
        int gb = gbase[b];
        for (int i = t; i < cb; i += 256) pairs[gb + i] = stag[lo + i];
    }
}

// Phase B: fine counting sort within one bucket, fully in LDS, then one
// coalesced full-line write of the bucket's csr slice.
__global__ __launch_bounds__(1024) void csr_sort(const unsigned* __restrict__ pairs,
                                                 const int* __restrict__ offs,
                                                 int* __restrict__ csr, int E, int N) {
    extern __shared__ unsigned stag2[];   // MAXB entries (80KB)
    __shared__ int ncur[BKT_NODES];
    const int b  = blockIdx.x;
    const int t  = threadIdx.x;
    const int n0 = b << BKT_SHIFT;
    const int n1 = min(n0 + BKT_NODES, N);
    const int base = offs[n0];
    const int end  = (n1 < N) ? offs[n1] : E;
    const int ne   = end - base;
    if (t < BKT_NODES) ncur[t] = (n0 + t < N) ? offs[n0 + t] - base : 0;
    __syncthreads();
    if (ne <= MAXB) {
        for (int i = t; i < ne; i += 1024) {
            unsigned p = pairs[base + i];
            int local  = p >> 17;
            int pos    = atomicAdd(&ncur[local], 1);
            stag2[pos] = p & 0x1FFFFu;
        }
        __syncthreads();
        for (int i = t; i < ne; i += 1024) csr[base + i] = (int)stag2[i];
    } else {  // safety fallback (never hit for random edges)
        for (int i = t; i < ne; i += 1024) {
            unsigned p = pairs[base + i];
            int local  = p >> 17;
            int pos    = atomicAdd(&ncur[local], 1);
            csr[base + pos] = (int)(p & 0x1FFFFu);
        }
    }
}

// G[row] = (X[row] @ W) * dinv[row].  X:[N,K], W:[K,64], G:[N,64].
template <int K>
__global__ __launch_bounds__(256) void gemm_scale(const float* __restrict__ X,
                                                  const float* __restrict__ W,
                                                  const float* __restrict__ dinv,
                                                  float* __restrict__ G, int N) {
    __shared__ float Ws[K * 64];
    __shared__ float Xs[32][K + 1];
    const int t  = threadIdx.x;
    const int r0 = blockIdx.x * 32;

    for (int i = t; i < K * 16; i += 256)
        ((float4*)Ws)[i] = ((const float4*)W)[i];

    for (int i = t; i < 32 * (K / 4); i += 256) {
        int row = i / (K / 4);
        int kk  = (i % (K / 4)) * 4;
        int gr  = r0 + row;
        float4 v = make_float4(0.f, 0.f, 0.f, 0.f);
        if (gr < N) v = *(const float4*)(X + (size_t)gr * K + kk);
        Xs[row][kk + 0] = v.x; Xs[row][kk + 1] = v.y;
        Xs[row][kk + 2] = v.z; Xs[row][kk + 3] = v.w;
    }
    __syncthreads();

    const int cg = (t & 15) * 4;
    const int ry = t >> 4;
    float4 a0 = make_float4(0.f, 0.f, 0.f, 0.f);
    float4 a1 = make_float4(0.f, 0.f, 0.f, 0.f);
#pragma unroll 8
    for (int k = 0; k < K; ++k) {
        float4 w = *(const float4*)&Ws[k * 64 + cg];
        float x0 = Xs[ry][k];
        float x1 = Xs[ry + 16][k];
        a0.x = fmaf(x0, w.x, a0.x); a0.y = fmaf(x0, w.y, a0.y);
        a0.z = fmaf(x0, w.z, a0.z); a0.w = fmaf(x0, w.w, a0.w);
        a1.x = fmaf(x1, w.x, a1.x); a1.y = fmaf(x1, w.y, a1.y);
        a1.z = fmaf(x1, w.z, a1.z); a1.w = fmaf(x1, w.w, a1.w);
    }

    int row0 = r0 + ry;
    if (row0 < N) {
        float s = dinv[row0];
        *(float4*)(G + (size_t)row0 * 64 + cg) =
            make_float4(a0.x * s, a0.y * s, a0.z * s, a0.w * s);
    }
    int row1 = r0 + ry + 16;
    if (row1 < N) {
        float s = dinv[row1];
        *(float4*)(G + (size_t)row1 * 64 + cg) =
            make_float4(a1.x * s, a1.y * s, a1.z * s, a1.w * s);
    }
}

// One wave per node, lane = feature column. Coalesced 256B gathers of G rows.
__global__ __launch_bounds__(256) void aggregate(const float* __restrict__ G,
                                                 const int* __restrict__ offs,
                                                 const int* __restrict__ cnt,
                                                 const int* __restrict__ csr,
                                                 const float* __restrict__ dinv,
                                                 const float* __restrict__ bias,
                                                 float* __restrict__ out, int N,
                                                 int do_relu) {
    int w    = (blockIdx.x * 256 + threadIdx.x) >> 6;
    int lane = threadIdx.x & 63;
    if (w >= N) return;
    int beg = offs[w];
    int num = cnt[w];
    float acc = G[(size_t)w * 64 + lane];  // self-loop term
    int e = 0;
    for (; e + 4 <= num; e += 4) {
        int s0 = csr[beg + e + 0];
        int s1 = csr[beg + e + 1];
        int s2 = csr[beg + e + 2];
        int s3 = csr[beg + e + 3];
        float g0 = G[(size_t)s0 * 64 + lane];
        float g1 = G[(size_t)s1 * 64 + lane];
        float g2 = G[(size_t)s2 * 64 + lane];
        float g3 = G[(size_t)s3 * 64 + lane];
        acc += g0; acc += g1; acc += g2; acc += g3;
    }
    for (; e < num; ++e) acc += G[(size_t)csr[beg + e] * 64 + lane];
    float v = fmaf(acc, dinv[w], bias[lane]);
    if (do_relu) v = fmaxf(v, 0.f);
    out[(size_t)w * 64 + lane] = v;
}

extern "C" void kernel_launch(void* const* d_in, const int* in_sizes, int n_in,
                              void* d_out, int out_size, void* d_ws, size_t ws_size,
                              hipStream_t stream) {
    const float* x  = (const float*)d_in[0];
    const int*   ei = (const int*)d_in[1];
    const float* W1 = (const float*)d_in[2];
    const float* b1 = (const float*)d_in[3];
    const float* W2 = (const float*)d_in[4];
    const float* b2 = (const float*)d_in[5];
    float* out = (float*)d_out;

    const int IN_CH = 128;
    const int N = in_sizes[0] / IN_CH;   // 100000
    const int E = in_sizes[1] / 2;       // 3200000
    const int* src = ei;
    const int* dst = ei + E;
    const int NB = (N + BKT_NODES - 1) >> BKT_SHIFT;  // 196

    char* ws = (char*)d_ws;
    size_t off = 0;
    auto take = [&](size_t bytes) -> char* {
        char* p = ws + off;
        off += (bytes + 255) & ~(size_t)255;
        return p;
    };
    int*   cnt   = (int*)take((size_t)N * 4);
    int*   bcur  = (int*)take(NBSH * 4);
    int*   offs  = (int*)take((size_t)N * 4);
    float* dinv  = (float*)take((size_t)N * 4);
    int*   bsums = (int*)take(512 * 4);
    int*   csr   = (int*)take((size_t)E * 4);
    float* g     = (float*)take((size_t)N * 64 * 4);
    float* a1    = (float*)take((size_t)N * 64 * 4);
    unsigned* pairs = (unsigned*)g;  // alias: pairs dead before gemm writes g

    const int nbN = (N + 255) / 256;
    const int nbE = (E + 255) / 256;
    const int nbC = (E + CHUNK - 1) / CHUNK;

    zero_counts<<<nbN, 256, 0, stream>>>(cnt, bcur, N);
    hist_kernel<<<nbE, 256, 0, stream>>>(dst, cnt, E, N);
    dinv_kernel<<<nbN, 256, 0, stream>>>(cnt, dinv, N);
    block_sums<<<nbN, 256, 0, stream>>>(cnt, bsums, N);
    scan_blocksums<<<1, 512, 0, stream>>>(bsums, nbN);
    scan_chunks<<<nbN, 256, 0, stream>>>(cnt, bsums, offs, N);
    bucket_bin<<<nbC, 256, 0, stream>>>(src, dst, offs, bcur, pairs, E, N, NB);
    csr_sort<<<NB, 1024, MAXB * 4, stream>>>(pairs, offs, csr, E, N);

    // layer 1
    gemm_scale<128><<<(N + 31) / 32, 256, 0, stream>>>(x, W1, dinv, g, N);
    aggregate<<<(N + 3) / 4, 256, 0, stream>>>(g, offs, cnt, csr, dinv, b1, a1, N, 1);
    // layer 2
    gemm_scale<64><<<(N + 31) / 32, 256, 0, stream>>>(a1, W2, dinv, g, N);
    aggregate<<<(N + 3) / 4, 256, 0, stream>>>(g, offs, cnt, csr, dinv, b2, out, N, 0);
}

// Round 3
// 490.926 us; speedup vs baseline: 1.4269x; 1.2350x over previous
//
#include <hip/hip_runtime.h>
#include <math.h>

// ---------------------------------------------------------------------------
// 2-layer GCN:  out = GCNConv(relu(GCNConv(x, W1, b1)), W2, b2)
// Factorization: g = (x@W) * dinv[row];  agg[d] = g[d] + sum_{s in in(d)} g[s];
//                out[d] = agg[d]*dinv[d] + b   (dinv = rsqrt(indeg+1))
//
// R1 lesson: naive per-node scatter -> 197MB partial-line writebacks (215us).
// R2 lesson: global per-node histogram atomics -> 99.8MB writebacks (128us).
// R3: NO per-node global atomics anywhere. Coarse 196-bucket histogram
// (LDS-staged, 196 atomics/block) -> bucket binning -> per-bucket LDS
// counting sort that ALSO produces cnt/offs/dinv as coalesced 512-wide runs.
// ---------------------------------------------------------------------------

#define BKT_SHIFT 9               // 512 nodes per bucket
#define BKT_NODES 512
#define NBSH      256             // >= bucket count (196)
#define CHUNK     8192            // edges per bucket_bin/coarse_hist block
#define MAXB      20480           // max edges/bucket for LDS sort (mean ~16.3k)

__global__ __launch_bounds__(256) void zero_small(int* __restrict__ bhist,
                                                  int* __restrict__ bcur) {
    int t = threadIdx.x;
    bhist[t] = 0;
    bcur[t]  = 0;
}

// Coarse histogram over 196 buckets: LDS accumulate, 196 global atomics/block.
__global__ __launch_bounds__(256) void coarse_hist(const int* __restrict__ dst,
                                                   int* __restrict__ bhist,
                                                   int E, int NB) {
    __shared__ int h[NBSH];
    const int t  = threadIdx.x;
    const int e0 = blockIdx.x * CHUNK;
    const int n  = min(CHUNK, E - e0);
    h[t] = 0;
    __syncthreads();
    for (int i = t; i < n; i += 256) atomicAdd(&h[dst[e0 + i] >> BKT_SHIFT], 1);
    __syncthreads();
    if (t < NB && h[t] > 0) atomicAdd(&bhist[t], h[t]);
}

// Exclusive scan of 196 bucket counts -> boffs[0..NB] (boffs[NB] = E).
__global__ __launch_bounds__(256) void scan196(const int* __restrict__ bhist,
                                               int* __restrict__ boffs, int NB, int E) {
    __shared__ int sh[256];
    int t = threadIdx.x;
    int orig = (t < NB) ? bhist[t] : 0;
    sh[t] = orig;
    __syncthreads();
    for (int d = 1; d < 256; d <<= 1) {
        int u = (t >= d) ? sh[t - d] : 0;
        __syncthreads();
        sh[t] += u;
        __syncthreads();
    }
    if (t < NB) boffs[t] = sh[t] - orig;  // exclusive
    if (t == NB) boffs[NB] = E;
    if (t == 255 && NB < 255) boffs[NB] = E;  // ensure written when NB<256
}

// Phase A: bin edges into buckets. Packed pair: (dst&511)<<17 | src  (src<2^17).
// All global writes are contiguous per-bucket runs from LDS staging.
__global__ __launch_bounds__(256) void bucket_bin(const int* __restrict__ src,
                                                  const int* __restrict__ dst,
                                                  const int* __restrict__ boffs,
                                                  int* __restrict__ bcur,
                                                  unsigned* __restrict__ pairs,
                                                  int E, int NB) {
    __shared__ unsigned stag[CHUNK];   // 32KB
    __shared__ int hist[NBSH];
    __shared__ int lofs[NBSH];
    __shared__ int lcur[NBSH];
    __shared__ int gbase[NBSH];
    const int t  = threadIdx.x;
    const int e0 = blockIdx.x * CHUNK;
    const int n  = min(CHUNK, E - e0);

    for (int i = t; i < NBSH; i += 256) hist[i] = 0;
    __syncthreads();
    for (int i = t; i < n; i += 256) atomicAdd(&hist[dst[e0 + i] >> BKT_SHIFT], 1);
    __syncthreads();
    int v = hist[t];
    lofs[t] = v;
    __syncthreads();
    for (int d = 1; d < 256; d <<= 1) {
        int u = (t >= d) ? lofs[t - d] : 0;
        __syncthreads();
        lofs[t] += u;
        __syncthreads();
    }
    if (t < NB) {
        lcur[t]  = lofs[t] - v;
        gbase[t] = (v > 0) ? boffs[t] + atomicAdd(&bcur[t], v) : 0;
    }
    __syncthreads();
    for (int i = t; i < n; i += 256) {
        int d = dst[e0 + i];
        int s = src[e0 + i];
        int b = d >> BKT_SHIFT;
        int p = atomicAdd(&lcur[b], 1);
        stag[p] = ((unsigned)(d & (BKT_NODES - 1)) << 17) | (unsigned)s;
    }
    __syncthreads();
    for (int b = 0; b < NB; ++b) {
        int cb = hist[b];
        if (cb == 0) continue;
        int lo = lofs[b] - cb;
        int gb = gbase[b];
        for (int i = t; i < cb; i += 256) pairs[gb + i] = stag[lo + i];
    }
}

// Phase B: per-bucket fine counting sort in LDS. Also emits cnt/offs/dinv for
// the bucket's 512 nodes as coalesced runs (replaces global histogram).
__global__ __launch_bounds__(1024) void csr_sort(const unsigned* __restrict__ pairs,
                                                 const int* __restrict__ boffs,
                                                 int* __restrict__ csr,
                                                 int* __restrict__ cnt,
                                                 int* __restrict__ offs,
                                                 float* __restrict__ dinv,
                                                 int N) {
    extern __shared__ unsigned stag2[];   // MAXB entries (80KB)
    __shared__ int lhist[BKT_NODES];
    __shared__ int lofs[BKT_NODES];
    __shared__ int ncur[BKT_NODES];
    const int b    = blockIdx.x;
    const int t    = threadIdx.x;
    const int n0   = b << BKT_SHIFT;
    const int base = boffs[b];
    const int ne   = boffs[b + 1] - base;

    if (t < BKT_NODES) lhist[t] = 0;
    __syncthreads();
    for (int i = t; i < ne; i += 1024) atomicAdd(&lhist[pairs[base + i] >> 17], 1);
    __syncthreads();
    // inclusive scan of lhist (512) with first 512 threads
    if (t < BKT_NODES) lofs[t] = lhist[t];
    __syncthreads();
    for (int d = 1; d < BKT_NODES; d <<= 1) {
        int u = (t < BKT_NODES && t >= d) ? lofs[t - d] : 0;
        __syncthreads();
        if (t < BKT_NODES) lofs[t] += u;
        __syncthreads();
    }
    if (t < BKT_NODES) {
        int node = n0 + t;
        int ex   = lofs[t] - lhist[t];   // exclusive
        ncur[t]  = ex;
        if (node < N) {
            cnt[node]  = lhist[t];
            offs[node] = base + ex;
            dinv[node] = rsqrtf((float)(lhist[t] + 1));
        }
    }
    __syncthreads();
    if (ne <= MAXB) {
        for (int i = t; i < ne; i += 1024) {
            unsigned p = pairs[base + i];
            int pos = atomicAdd(&ncur[p >> 17], 1);
            stag2[pos] = p & 0x1FFFFu;
        }
        __syncthreads();
        for (int i = t; i < ne; i += 1024) csr[base + i] = (int)stag2[i];
    } else {  // safety fallback
        for (int i = t; i < ne; i += 1024) {
            unsigned p = pairs[base + i];
            int pos = atomicAdd(&ncur[p >> 17], 1);
            csr[base + pos] = (int)(p & 0x1FFFFu);
        }
    }
}

// G[row] = (X[row] @ W) * dinv[row].  X:[N,K], W:[K,64], G:[N,64].
template <int K>
__global__ __launch_bounds__(256) void gemm_scale(const float* __restrict__ X,
                                                  const float* __restrict__ W,
                                                  const float* __restrict__ dinv,
                                                  float* __restrict__ G, int N) {
    __shared__ float Ws[K * 64];
    __shared__ float Xs[32][K + 1];
    const int t  = threadIdx.x;
    const int r0 = blockIdx.x * 32;

    for (int i = t; i < K * 16; i += 256)
        ((float4*)Ws)[i] = ((const float4*)W)[i];

    for (int i = t; i < 32 * (K / 4); i += 256) {
        int row = i / (K / 4);
        int kk  = (i % (K / 4)) * 4;
        int gr  = r0 + row;
        float4 v = make_float4(0.f, 0.f, 0.f, 0.f);
        if (gr < N) v = *(const float4*)(X + (size_t)gr * K + kk);
        Xs[row][kk + 0] = v.x; Xs[row][kk + 1] = v.y;
        Xs[row][kk + 2] = v.z; Xs[row][kk + 3] = v.w;
    }
    __syncthreads();

    const int cg = (t & 15) * 4;
    const int ry = t >> 4;
    float4 a0 = make_float4(0.f, 0.f, 0.f, 0.f);
    float4 a1 = make_float4(0.f, 0.f, 0.f, 0.f);
#pragma unroll 8
    for (int k = 0; k < K; ++k) {
        float4 w = *(const float4*)&Ws[k * 64 + cg];
        float x0 = Xs[ry][k];
        float x1 = Xs[ry + 16][k];
        a0.x = fmaf(x0, w.x, a0.x); a0.y = fmaf(x0, w.y, a0.y);
        a0.z = fmaf(x0, w.z, a0.z); a0.w = fmaf(x0, w.w, a0.w);
        a1.x = fmaf(x1, w.x, a1.x); a1.y = fmaf(x1, w.y, a1.y);
        a1.z = fmaf(x1, w.z, a1.z); a1.w = fmaf(x1, w.w, a1.w);
    }

    int row0 = r0 + ry;
    if (row0 < N) {
        float s = dinv[row0];
        *(float4*)(G + (size_t)row0 * 64 + cg) =
            make_float4(a0.x * s, a0.y * s, a0.z * s, a0.w * s);
    }
    int row1 = r0 + ry + 16;
    if (row1 < N) {
        float s = dinv[row1];
        *(float4*)(G + (size_t)row1 * 64 + cg) =
            make_float4(a1.x * s, a1.y * s, a1.z * s, a1.w * s);
    }
}

// One wave per node, lane = feature column. Coalesced 256B gathers of G rows.
__global__ __launch_bounds__(256) void aggregate(const float* __restrict__ G,
                                                 const int* __restrict__ offs,
                                                 const int* __restrict__ cnt,
                                                 const int* __restrict__ csr,
                                                 const float* __restrict__ dinv,
                                                 const float* __restrict__ bias,
                                                 float* __restrict__ out, int N,
                                                 int do_relu) {
    int w    = (blockIdx.x * 256 + threadIdx.x) >> 6;
    int lane = threadIdx.x & 63;
    if (w >= N) return;
    int beg = offs[w];
    int num = cnt[w];
    float acc = G[(size_t)w * 64 + lane];  // self-loop term
    int e = 0;
    for (; e + 4 <= num; e += 4) {
        int s0 = csr[beg + e + 0];
        int s1 = csr[beg + e + 1];
        int s2 = csr[beg + e + 2];
        int s3 = csr[beg + e + 3];
        float g0 = G[(size_t)s0 * 64 + lane];
        float g1 = G[(size_t)s1 * 64 + lane];
        float g2 = G[(size_t)s2 * 64 + lane];
        float g3 = G[(size_t)s3 * 64 + lane];
        acc += g0; acc += g1; acc += g2; acc += g3;
    }
    for (; e < num; ++e) acc += G[(size_t)csr[beg + e] * 64 + lane];
    float v = fmaf(acc, dinv[w], bias[lane]);
    if (do_relu) v = fmaxf(v, 0.f);
    out[(size_t)w * 64 + lane] = v;
}

extern "C" void kernel_launch(void* const* d_in, const int* in_sizes, int n_in,
                              void* d_out, int out_size, void* d_ws, size_t ws_size,
                              hipStream_t stream) {
    const float* x  = (const float*)d_in[0];
    const int*   ei = (const int*)d_in[1];
    const float* W1 = (const float*)d_in[2];
    const float* b1 = (const float*)d_in[3];
    const float* W2 = (const float*)d_in[4];
    const float* b2 = (const float*)d_in[5];
    float* out = (float*)d_out;

    const int IN_CH = 128;
    const int N = in_sizes[0] / IN_CH;   // 100000
    const int E = in_sizes[1] / 2;       // 3200000
    const int* src = ei;
    const int* dst = ei + E;
    const int NB = (N + BKT_NODES - 1) >> BKT_SHIFT;  // 196

    char* ws = (char*)d_ws;
    size_t off = 0;
    auto take = [&](size_t bytes) -> char* {
        char* p = ws + off;
        off += (bytes + 255) & ~(size_t)255;
        return p;
    };
    int*   cnt   = (int*)take((size_t)N * 4);
    int*   offs  = (int*)take((size_t)N * 4);
    float* dinv  = (float*)take((size_t)N * 4);
    int*   bhist = (int*)take(NBSH * 4);
    int*   boffs = (int*)take((NBSH + 1) * 4);
    int*   bcur  = (int*)take(NBSH * 4);
    int*   csr   = (int*)take((size_t)E * 4);
    float* g     = (float*)take((size_t)N * 64 * 4);
    float* a1    = (float*)take((size_t)N * 64 * 4);
    unsigned* pairs = (unsigned*)g;  // alias: pairs dead before gemm writes g

    const int nbC = (E + CHUNK - 1) / CHUNK;

    zero_small<<<1, 256, 0, stream>>>(bhist, bcur);
    coarse_hist<<<nbC, 256, 0, stream>>>(dst, bhist, E, NB);
    scan196<<<1, 256, 0, stream>>>(bhist, boffs, NB, E);
    bucket_bin<<<nbC, 256, 0, stream>>>(src, dst, boffs, bcur, pairs, E, NB);
    csr_sort<<<NB, 1024, MAXB * 4, stream>>>(pairs, boffs, csr, cnt, offs, dinv, N);

    // layer 1
    gemm_scale<128><<<(N + 31) / 32, 256, 0, stream>>>(x, W1, dinv, g, N);
    aggregate<<<(N + 3) / 4, 256, 0, stream>>>(g, offs, cnt, csr, dinv, b1, a1, N, 1);
    // layer 2
    gemm_scale<64><<<(N + 31) / 32, 256, 0, stream>>>(a1, W2, dinv, g, N);
    aggregate<<<(N + 3) / 4, 256, 0, stream>>>(g, offs, cnt, csr, dinv, b2, out, N, 0);
}

// Round 4
// 401.951 us; speedup vs baseline: 1.7427x; 1.2214x over previous
//
#include <hip/hip_runtime.h>
#include <math.h>

// ---------------------------------------------------------------------------
// 2-layer GCN:  out = GCNConv(relu(GCNConv(x, W1, b1)), W2, b2)
// Factorization: g = (x@W) * dinv[row];  agg[d] = g[d] + sum_{s in in(d)} g[s];
//                out[d] = agg[d]*dinv[d] + b   (dinv = rsqrt(indeg+1))
//
// R1: naive per-node scatter -> 197MB partial-line writebacks (215us). Fixed.
// R2: global per-node histogram atomics -> 99.8MB writebacks (128us). Fixed.
// R3 counters: aggregate = 119us x2, FETCH 364MB (random 256B row gathers miss
//   per-XCD L2; traffic is intrinsic E*row_bytes). R4: G stored in bf16 ->
//   128B rows, halves gather traffic. fp32 accumulate (err budget ~2e-3 vs
//   6e-3 threshold). Also: bucket_bin copy-out parallelized wave-per-bucket.
// ---------------------------------------------------------------------------

#define BKT_SHIFT 9               // 512 nodes per bucket
#define BKT_NODES 512
#define NBSH      256             // >= bucket count (196)
#define CHUNK     8192            // edges per bucket_bin/coarse_hist block
#define MAXB      20480           // max edges/bucket for LDS sort (mean ~16.3k)

typedef unsigned short ushort_t;

static __device__ __forceinline__ unsigned short f2bf(float f) {
    unsigned u = __float_as_uint(f);
    unsigned r = (u + 0x7FFFu + ((u >> 16) & 1u)) >> 16;   // RNE
    return (unsigned short)r;
}
static __device__ __forceinline__ float bf2f(unsigned short h) {
    return __uint_as_float(((unsigned)h) << 16);
}

struct ushort4_t { unsigned short x, y, z, w; };

__global__ __launch_bounds__(256) void zero_small(int* __restrict__ bhist,
                                                  int* __restrict__ bcur) {
    int t = threadIdx.x;
    bhist[t] = 0;
    bcur[t]  = 0;
}

// Coarse histogram over 196 buckets: LDS accumulate, 196 global atomics/block.
__global__ __launch_bounds__(256) void coarse_hist(const int* __restrict__ dst,
                                                   int* __restrict__ bhist,
                                                   int E, int NB) {
    __shared__ int h[NBSH];
    const int t  = threadIdx.x;
    const int e0 = blockIdx.x * CHUNK;
    const int n  = min(CHUNK, E - e0);
    h[t] = 0;
    __syncthreads();
    for (int i = t; i < n; i += 256) atomicAdd(&h[dst[e0 + i] >> BKT_SHIFT], 1);
    __syncthreads();
    if (t < NB && h[t] > 0) atomicAdd(&bhist[t], h[t]);
}

// Exclusive scan of bucket counts -> boffs[0..NB] (boffs[NB] = E).
__global__ __launch_bounds__(256) void scan196(const int* __restrict__ bhist,
                                               int* __restrict__ boffs, int NB, int E) {
    __shared__ int sh[256];
    int t = threadIdx.x;
    int orig = (t < NB) ? bhist[t] : 0;
    sh[t] = orig;
    __syncthreads();
    for (int d = 1; d < 256; d <<= 1) {
        int u = (t >= d) ? sh[t - d] : 0;
        __syncthreads();
        sh[t] += u;
        __syncthreads();
    }
    if (t < NB) boffs[t] = sh[t] - orig;  // exclusive
    if (t == NB) boffs[NB] = E;
    if (t == 255 && NB < 255) boffs[NB] = E;
}

// Phase A: bin edges into buckets. Packed pair: (dst&511)<<17 | src  (src<2^17).
__global__ __launch_bounds__(256) void bucket_bin(const int* __restrict__ src,
                                                  const int* __restrict__ dst,
                                                  const int* __restrict__ boffs,
                                                  int* __restrict__ bcur,
                                                  unsigned* __restrict__ pairs,
                                                  int E, int NB) {
    __shared__ unsigned stag[CHUNK];   // 32KB
    __shared__ int hist[NBSH];
    __shared__ int lofs[NBSH];
    __shared__ int lcur[NBSH];
    __shared__ int gbase[NBSH];
    const int t  = threadIdx.x;
    const int e0 = blockIdx.x * CHUNK;
    const int n  = min(CHUNK, E - e0);

    for (int i = t; i < NBSH; i += 256) hist[i] = 0;
    __syncthreads();
    for (int i = t; i < n; i += 256) atomicAdd(&hist[dst[e0 + i] >> BKT_SHIFT], 1);
    __syncthreads();
    int v = hist[t];
    lofs[t] = v;
    __syncthreads();
    for (int d = 1; d < 256; d <<= 1) {
        int u = (t >= d) ? lofs[t - d] : 0;
        __syncthreads();
        lofs[t] += u;
        __syncthreads();
    }
    if (t < NB) {
        lcur[t]  = lofs[t] - v;
        gbase[t] = (v > 0) ? boffs[t] + atomicAdd(&bcur[t], v) : 0;
    }
    __syncthreads();
    for (int i = t; i < n; i += 256) {
        int d = dst[e0 + i];
        int s = src[e0 + i];
        int b = d >> BKT_SHIFT;
        int p = atomicAdd(&lcur[b], 1);
        stag[p] = ((unsigned)(d & (BKT_NODES - 1)) << 17) | (unsigned)s;
    }
    __syncthreads();
    // copy-out: wave-per-bucket (parallel across the 4 waves, 64-lane runs)
    const int wv = t >> 6, ln = t & 63;
    for (int b = wv; b < NB; b += 4) {
        int cb = hist[b];
        if (cb == 0) continue;
        int lo = lofs[b] - cb;
        int gb = gbase[b];
        for (int i = ln; i < cb; i += 64) pairs[gb + i] = stag[lo + i];
    }
}

// Phase B: per-bucket fine counting sort in LDS; emits cnt/offs/dinv coalesced.
__global__ __launch_bounds__(1024) void csr_sort(const unsigned* __restrict__ pairs,
                                                 const int* __restrict__ boffs,
                                                 int* __restrict__ csr,
                                                 int* __restrict__ cnt,
                                                 int* __restrict__ offs,
                                                 float* __restrict__ dinv,
                                                 int N) {
    extern __shared__ unsigned stag2[];   // MAXB entries (80KB)
    __shared__ int lhist[BKT_NODES];
    __shared__ int lofs[BKT_NODES];
    __shared__ int ncur[BKT_NODES];
    const int b    = blockIdx.x;
    const int t    = threadIdx.x;
    const int n0   = b << BKT_SHIFT;
    const int base = boffs[b];
    const int ne   = boffs[b + 1] - base;

    if (t < BKT_NODES) lhist[t] = 0;
    __syncthreads();
    for (int i = t; i < ne; i += 1024) atomicAdd(&lhist[pairs[base + i] >> 17], 1);
    __syncthreads();
    if (t < BKT_NODES) lofs[t] = lhist[t];
    __syncthreads();
    for (int d = 1; d < BKT_NODES; d <<= 1) {
        int u = (t < BKT_NODES && t >= d) ? lofs[t - d] : 0;
        __syncthreads();
        if (t < BKT_NODES) lofs[t] += u;
        __syncthreads();
    }
    if (t < BKT_NODES) {
        int node = n0 + t;
        int ex   = lofs[t] - lhist[t];
        ncur[t]  = ex;
        if (node < N) {
            cnt[node]  = lhist[t];
            offs[node] = base + ex;
            dinv[node] = rsqrtf((float)(lhist[t] + 1));
        }
    }
    __syncthreads();
    if (ne <= MAXB) {
        for (int i = t; i < ne; i += 1024) {
            unsigned p = pairs[base + i];
            int pos = atomicAdd(&ncur[p >> 17], 1);
            stag2[pos] = p & 0x1FFFFu;
        }
        __syncthreads();
        for (int i = t; i < ne; i += 1024) csr[base + i] = (int)stag2[i];
    } else {  // safety fallback
        for (int i = t; i < ne; i += 1024) {
            unsigned p = pairs[base + i];
            int pos = atomicAdd(&ncur[p >> 17], 1);
            csr[base + pos] = (int)(p & 0x1FFFFu);
        }
    }
}

// G[row] = bf16( (X[row] @ W) * dinv[row] ).  X:[N,K] f32, W:[K,64], G:[N,64] bf16.
template <int K>
__global__ __launch_bounds__(256) void gemm_scale(const float* __restrict__ X,
                                                  const float* __restrict__ W,
                                                  const float* __restrict__ dinv,
                                                  ushort_t* __restrict__ G, int N) {
    __shared__ float Ws[K * 64];
    __shared__ float Xs[32][K + 1];
    const int t  = threadIdx.x;
    const int r0 = blockIdx.x * 32;

    for (int i = t; i < K * 16; i += 256)
        ((float4*)Ws)[i] = ((const float4*)W)[i];

    for (int i = t; i < 32 * (K / 4); i += 256) {
        int row = i / (K / 4);
        int kk  = (i % (K / 4)) * 4;
        int gr  = r0 + row;
        float4 v = make_float4(0.f, 0.f, 0.f, 0.f);
        if (gr < N) v = *(const float4*)(X + (size_t)gr * K + kk);
        Xs[row][kk + 0] = v.x; Xs[row][kk + 1] = v.y;
        Xs[row][kk + 2] = v.z; Xs[row][kk + 3] = v.w;
    }
    __syncthreads();

    const int cg = (t & 15) * 4;
    const int ry = t >> 4;
    float4 a0 = make_float4(0.f, 0.f, 0.f, 0.f);
    float4 a1 = make_float4(0.f, 0.f, 0.f, 0.f);
#pragma unroll 8
    for (int k = 0; k < K; ++k) {
        float4 w = *(const float4*)&Ws[k * 64 + cg];
        float x0 = Xs[ry][k];
        float x1 = Xs[ry + 16][k];
        a0.x = fmaf(x0, w.x, a0.x); a0.y = fmaf(x0, w.y, a0.y);
        a0.z = fmaf(x0, w.z, a0.z); a0.w = fmaf(x0, w.w, a0.w);
        a1.x = fmaf(x1, w.x, a1.x); a1.y = fmaf(x1, w.y, a1.y);
        a1.z = fmaf(x1, w.z, a1.z); a1.w = fmaf(x1, w.w, a1.w);
    }

    int row0 = r0 + ry;
    if (row0 < N) {
        float s = dinv[row0];
        ushort4_t o = { f2bf(a0.x * s), f2bf(a0.y * s), f2bf(a0.z * s), f2bf(a0.w * s) };
        *(ushort4_t*)(G + (size_t)row0 * 64 + cg) = o;
    }
    int row1 = r0 + ry + 16;
    if (row1 < N) {
        float s = dinv[row1];
        ushort4_t o = { f2bf(a1.x * s), f2bf(a1.y * s), f2bf(a1.z * s), f2bf(a1.w * s) };
        *(ushort4_t*)(G + (size_t)row1 * 64 + cg) = o;
    }
}

// One wave per node, lane = feature column. 128B bf16 row gathers, fp32 acc.
__global__ __launch_bounds__(256) void aggregate(const ushort_t* __restrict__ G,
                                                 const int* __restrict__ offs,
                                                 const int* __restrict__ cnt,
                                                 const int* __restrict__ csr,
                                                 const float* __restrict__ dinv,
                                                 const float* __restrict__ bias,
                                                 float* __restrict__ out, int N,
                                                 int do_relu) {
    int w    = (blockIdx.x * 256 + threadIdx.x) >> 6;
    int lane = threadIdx.x & 63;
    if (w >= N) return;
    int beg = offs[w];
    int num = cnt[w];
    float acc = bf2f(G[(size_t)w * 64 + lane]);  // self-loop term
    int e = 0;
    for (; e + 8 <= num; e += 8) {
        int s0 = csr[beg + e + 0];
        int s1 = csr[beg + e + 1];
        int s2 = csr[beg + e + 2];
        int s3 = csr[beg + e + 3];
        int s4 = csr[beg + e + 4];
        int s5 = csr[beg + e + 5];
        int s6 = csr[beg + e + 6];
        int s7 = csr[beg + e + 7];
        ushort_t u0 = G[(size_t)s0 * 64 + lane];
        ushort_t u1 = G[(size_t)s1 * 64 + lane];
        ushort_t u2 = G[(size_t)s2 * 64 + lane];
        ushort_t u3 = G[(size_t)s3 * 64 + lane];
        ushort_t u4 = G[(size_t)s4 * 64 + lane];
        ushort_t u5 = G[(size_t)s5 * 64 + lane];
        ushort_t u6 = G[(size_t)s6 * 64 + lane];
        ushort_t u7 = G[(size_t)s7 * 64 + lane];
        acc += bf2f(u0); acc += bf2f(u1); acc += bf2f(u2); acc += bf2f(u3);
        acc += bf2f(u4); acc += bf2f(u5); acc += bf2f(u6); acc += bf2f(u7);
    }
    for (; e < num; ++e) acc += bf2f(G[(size_t)csr[beg + e] * 64 + lane]);
    float v = fmaf(acc, dinv[w], bias[lane]);
    if (do_relu) v = fmaxf(v, 0.f);
    out[(size_t)w * 64 + lane] = v;
}

extern "C" void kernel_launch(void* const* d_in, const int* in_sizes, int n_in,
                              void* d_out, int out_size, void* d_ws, size_t ws_size,
                              hipStream_t stream) {
    const float* x  = (const float*)d_in[0];
    const int*   ei = (const int*)d_in[1];
    const float* W1 = (const float*)d_in[2];
    const float* b1 = (const float*)d_in[3];
    const float* W2 = (const float*)d_in[4];
    const float* b2 = (const float*)d_in[5];
    float* out = (float*)d_out;

    const int IN_CH = 128;
    const int N = in_sizes[0] / IN_CH;   // 100000
    const int E = in_sizes[1] / 2;       // 3200000
    const int* src = ei;
    const int* dst = ei + E;
    const int NB = (N + BKT_NODES - 1) >> BKT_SHIFT;  // 196

    char* ws = (char*)d_ws;
    size_t off = 0;
    auto take = [&](size_t bytes) -> char* {
        char* p = ws + off;
        off += (bytes + 255) & ~(size_t)255;
        return p;
    };
    int*      cnt   = (int*)take((size_t)N * 4);
    int*      offs  = (int*)take((size_t)N * 4);
    float*    dinv  = (float*)take((size_t)N * 4);
    int*      bhist = (int*)take(NBSH * 4);
    int*      boffs = (int*)take((NBSH + 1) * 4);
    int*      bcur  = (int*)take(NBSH * 4);
    int*      csr   = (int*)take((size_t)E * 4);
    ushort_t* g     = (ushort_t*)take((size_t)E * 4);       // >= N*64*2; aliases pairs
    float*    a1    = (float*)take((size_t)N * 64 * 4);
    unsigned* pairs = (unsigned*)g;  // pairs dead before gemm writes g

    const int nbC = (E + CHUNK - 1) / CHUNK;

    zero_small<<<1, 256, 0, stream>>>(bhist, bcur);
    coarse_hist<<<nbC, 256, 0, stream>>>(dst, bhist, E, NB);
    scan196<<<1, 256, 0, stream>>>(bhist, boffs, NB, E);
    bucket_bin<<<nbC, 256, 0, stream>>>(src, dst, boffs, bcur, pairs, E, NB);
    csr_sort<<<NB, 1024, MAXB * 4, stream>>>(pairs, boffs, csr, cnt, offs, dinv, N);

    // layer 1
    gemm_scale<128><<<(N + 31) / 32, 256, 0, stream>>>(x, W1, dinv, g, N);
    aggregate<<<(N + 3) / 4, 256, 0, stream>>>(g, offs, cnt, csr, dinv, b1, a1, N, 1);
    // layer 2
    gemm_scale<64><<<(N + 31) / 32, 256, 0, stream>>>(a1, W2, dinv, g, N);
    aggregate<<<(N + 3) / 4, 256, 0, stream>>>(g, offs, cnt, csr, dinv, b2, out, N, 0);
}

// Round 5
// 342.403 us; speedup vs baseline: 2.0458x; 1.1739x over previous
//
#include <hip/hip_runtime.h>
#include <math.h>

// ---------------------------------------------------------------------------
// 2-layer GCN:  out = GCNConv(relu(GCNConv(x, W1, b1)), W2, b2)
// Factorization: g = (x@W) * dinv[row];  agg[d] = g[d] + sum_{s in in(d)} g[s];
//                out[d] = agg[d]*dinv[d] + b   (dinv = rsqrt(indeg+1))
//
// R1: naive per-node scatter -> 197MB partial-line writebacks. Fixed (bucket sort).
// R2: global per-node histogram atomics -> 99.8MB writebacks. Fixed (LDS sort).
// R3: fp32 gathers 364MB TCC fetch, 119us x2. R4: bf16 G rows (128B) -> 162MB.
// R4 counters: dur only 90us (pred 60) @1.8TB/s, VALUBusy 40% -> latency/MLP
//   bound, one ushort gather per edge. R5: dwordx4 gathers, 8 edges per wave
//   instruction (grp=lane>>3 edge, sub=lane&7 16B chunk), shfl_xor reduce.
// ---------------------------------------------------------------------------

#define BKT_SHIFT 9               // 512 nodes per bucket
#define BKT_NODES 512
#define NBSH      256             // >= bucket count (196)
#define CHUNK     8192            // edges per bucket_bin/coarse_hist block
#define MAXB      20480           // max edges/bucket for LDS sort (mean ~16.3k)

typedef unsigned short ushort_t;

static __device__ __forceinline__ unsigned short f2bf(float f) {
    unsigned u = __float_as_uint(f);
    unsigned r = (u + 0x7FFFu + ((u >> 16) & 1u)) >> 16;   // RNE
    return (unsigned short)r;
}
static __device__ __forceinline__ float bf_lo(unsigned u) {
    return __uint_as_float(u << 16);
}
static __device__ __forceinline__ float bf_hi(unsigned u) {
    return __uint_as_float(u & 0xFFFF0000u);
}

struct ushort4_t { unsigned short x, y, z, w; };

__global__ __launch_bounds__(256) void zero_small(int* __restrict__ bhist,
                                                  int* __restrict__ bcur) {
    int t = threadIdx.x;
    bhist[t] = 0;
    bcur[t]  = 0;
}

// Coarse histogram over 196 buckets: LDS accumulate, 196 global atomics/block.
__global__ __launch_bounds__(256) void coarse_hist(const int* __restrict__ dst,
                                                   int* __restrict__ bhist,
                                                   int E, int NB) {
    __shared__ int h[NBSH];
    const int t  = threadIdx.x;
    const int e0 = blockIdx.x * CHUNK;
    const int n  = min(CHUNK, E - e0);
    h[t] = 0;
    __syncthreads();
    for (int i = t; i < n; i += 256) atomicAdd(&h[dst[e0 + i] >> BKT_SHIFT], 1);
    __syncthreads();
    if (t < NB && h[t] > 0) atomicAdd(&bhist[t], h[t]);
}

// Exclusive scan of bucket counts -> boffs[0..NB] (boffs[NB] = E).
__global__ __launch_bounds__(256) void scan196(const int* __restrict__ bhist,
                                               int* __restrict__ boffs, int NB, int E) {
    __shared__ int sh[256];
    int t = threadIdx.x;
    int orig = (t < NB) ? bhist[t] : 0;
    sh[t] = orig;
    __syncthreads();
    for (int d = 1; d < 256; d <<= 1) {
        int u = (t >= d) ? sh[t - d] : 0;
        __syncthreads();
        sh[t] += u;
        __syncthreads();
    }
    if (t < NB) boffs[t] = sh[t] - orig;  // exclusive
    if (t == NB) boffs[NB] = E;
    if (t == 255 && NB < 255) boffs[NB] = E;
}

// Phase A: bin edges into buckets. Packed pair: (dst&511)<<17 | src  (src<2^17).
__global__ __launch_bounds__(256) void bucket_bin(const int* __restrict__ src,
                                                  const int* __restrict__ dst,
                                                  const int* __restrict__ boffs,
                                                  int* __restrict__ bcur,
                                                  unsigned* __restrict__ pairs,
                                                  int E, int NB) {
    __shared__ unsigned stag[CHUNK];   // 32KB
    __shared__ int hist[NBSH];
    __shared__ int lofs[NBSH];
    __shared__ int lcur[NBSH];
    __shared__ int gbase[NBSH];
    const int t  = threadIdx.x;
    const int e0 = blockIdx.x * CHUNK;
    const int n  = min(CHUNK, E - e0);

    for (int i = t; i < NBSH; i += 256) hist[i] = 0;
    __syncthreads();
    for (int i = t; i < n; i += 256) atomicAdd(&hist[dst[e0 + i] >> BKT_SHIFT], 1);
    __syncthreads();
    int v = hist[t];
    lofs[t] = v;
    __syncthreads();
    for (int d = 1; d < 256; d <<= 1) {
        int u = (t >= d) ? lofs[t - d] : 0;
        __syncthreads();
        lofs[t] += u;
        __syncthreads();
    }
    if (t < NB) {
        lcur[t]  = lofs[t] - v;
        gbase[t] = (v > 0) ? boffs[t] + atomicAdd(&bcur[t], v) : 0;
    }
    __syncthreads();
    for (int i = t; i < n; i += 256) {
        int d = dst[e0 + i];
        int s = src[e0 + i];
        int b = d >> BKT_SHIFT;
        int p = atomicAdd(&lcur[b], 1);
        stag[p] = ((unsigned)(d & (BKT_NODES - 1)) << 17) | (unsigned)s;
    }
    __syncthreads();
    // copy-out: wave-per-bucket (parallel across the 4 waves, 64-lane runs)
    const int wv = t >> 6, ln = t & 63;
    for (int b = wv; b < NB; b += 4) {
        int cb = hist[b];
        if (cb == 0) continue;
        int lo = lofs[b] - cb;
        int gb = gbase[b];
        for (int i = ln; i < cb; i += 64) pairs[gb + i] = stag[lo + i];
    }
}

// Phase B: per-bucket fine counting sort in LDS; emits cnt/offs/dinv coalesced.
__global__ __launch_bounds__(1024) void csr_sort(const unsigned* __restrict__ pairs,
                                                 const int* __restrict__ boffs,
                                                 int* __restrict__ csr,
                                                 int* __restrict__ cnt,
                                                 int* __restrict__ offs,
                                                 float* __restrict__ dinv,
                                                 int N) {
    extern __shared__ unsigned stag2[];   // MAXB entries (80KB)
    __shared__ int lhist[BKT_NODES];
    __shared__ int lofs[BKT_NODES];
    __shared__ int ncur[BKT_NODES];
    const int b    = blockIdx.x;
    const int t    = threadIdx.x;
    const int n0   = b << BKT_SHIFT;
    const int base = boffs[b];
    const int ne   = boffs[b + 1] - base;

    if (t < BKT_NODES) lhist[t] = 0;
    __syncthreads();
    for (int i = t; i < ne; i += 1024) atomicAdd(&lhist[pairs[base + i] >> 17], 1);
    __syncthreads();
    if (t < BKT_NODES) lofs[t] = lhist[t];
    __syncthreads();
    for (int d = 1; d < BKT_NODES; d <<= 1) {
        int u = (t < BKT_NODES && t >= d) ? lofs[t - d] : 0;
        __syncthreads();
        if (t < BKT_NODES) lofs[t] += u;
        __syncthreads();
    }
    if (t < BKT_NODES) {
        int node = n0 + t;
        int ex   = lofs[t] - lhist[t];
        ncur[t]  = ex;
        if (node < N) {
            cnt[node]  = lhist[t];
            offs[node] = base + ex;
            dinv[node] = rsqrtf((float)(lhist[t] + 1));
        }
    }
    __syncthreads();
    if (ne <= MAXB) {
        for (int i = t; i < ne; i += 1024) {
            unsigned p = pairs[base + i];
            int pos = atomicAdd(&ncur[p >> 17], 1);
            stag2[pos] = p & 0x1FFFFu;
        }
        __syncthreads();
        for (int i = t; i < ne; i += 1024) csr[base + i] = (int)stag2[i];
    } else {  // safety fallback
        for (int i = t; i < ne; i += 1024) {
            unsigned p = pairs[base + i];
            int pos = atomicAdd(&ncur[p >> 17], 1);
            csr[base + pos] = (int)(p & 0x1FFFFu);
        }
    }
}

// G[row] = bf16( (X[row] @ W) * dinv[row] ).  X:[N,K] f32, W:[K,64], G:[N,64] bf16.
template <int K>
__global__ __launch_bounds__(256) void gemm_scale(const float* __restrict__ X,
                                                  const float* __restrict__ W,
                                                  const float* __restrict__ dinv,
                                                  ushort_t* __restrict__ G, int N) {
    __shared__ float Ws[K * 64];
    __shared__ float Xs[32][K + 1];
    const int t  = threadIdx.x;
    const int r0 = blockIdx.x * 32;

    for (int i = t; i < K * 16; i += 256)
        ((float4*)Ws)[i] = ((const float4*)W)[i];

    for (int i = t; i < 32 * (K / 4); i += 256) {
        int row = i / (K / 4);
        int kk  = (i % (K / 4)) * 4;
        int gr  = r0 + row;
        float4 v = make_float4(0.f, 0.f, 0.f, 0.f);
        if (gr < N) v = *(const float4*)(X + (size_t)gr * K + kk);
        Xs[row][kk + 0] = v.x; Xs[row][kk + 1] = v.y;
        Xs[row][kk + 2] = v.z; Xs[row][kk + 3] = v.w;
    }
    __syncthreads();

    const int cg = (t & 15) * 4;
    const int ry = t >> 4;
    float4 a0 = make_float4(0.f, 0.f, 0.f, 0.f);
    float4 a1 = make_float4(0.f, 0.f, 0.f, 0.f);
#pragma unroll 8
    for (int k = 0; k < K; ++k) {
        float4 w = *(const float4*)&Ws[k * 64 + cg];
        float x0 = Xs[ry][k];
        float x1 = Xs[ry + 16][k];
        a0.x = fmaf(x0, w.x, a0.x); a0.y = fmaf(x0, w.y, a0.y);
        a0.z = fmaf(x0, w.z, a0.z); a0.w = fmaf(x0, w.w, a0.w);
        a1.x = fmaf(x1, w.x, a1.x); a1.y = fmaf(x1, w.y, a1.y);
        a1.z = fmaf(x1, w.z, a1.z); a1.w = fmaf(x1, w.w, a1.w);
    }

    int row0 = r0 + ry;
    if (row0 < N) {
        float s = dinv[row0];
        ushort4_t o = { f2bf(a0.x * s), f2bf(a0.y * s), f2bf(a0.z * s), f2bf(a0.w * s) };
        *(ushort4_t*)(G + (size_t)row0 * 64 + cg) = o;
    }
    int row1 = r0 + ry + 16;
    if (row1 < N) {
        float s = dinv[row1];
        ushort4_t o = { f2bf(a1.x * s), f2bf(a1.y * s), f2bf(a1.z * s), f2bf(a1.w * s) };
        *(ushort4_t*)(G + (size_t)row1 * 64 + cg) = o;
    }
}

// Wave per node; 8 edges per gather instruction. grp=lane>>3 picks the edge,
// sub=lane&7 picks the 16B chunk (8 bf16 cols) of the 128B row. Each dwordx4
// gather moves 1024B (8 rows). Cross-group sum via shfl_xor butterfly.
__global__ __launch_bounds__(256) void aggregate(const ushort_t* __restrict__ G,
                                                 const int* __restrict__ offs,
                                                 const int* __restrict__ cnt,
                                                 const int* __restrict__ csr,
                                                 const float* __restrict__ dinv,
                                                 const float* __restrict__ bias,
                                                 float* __restrict__ out, int N,
                                                 int do_relu) {
    int w    = (blockIdx.x * 256 + threadIdx.x) >> 6;
    int lane = threadIdx.x & 63;
    if (w >= N) return;
    const int grp = lane >> 3;   // which edge of the batch of 8
    const int sub = lane & 7;    // which 16B chunk of the row
    const int beg = offs[w];
    const int num = cnt[w];

    float acc[8] = {0.f, 0.f, 0.f, 0.f, 0.f, 0.f, 0.f, 0.f};
    // self-loop: group 0 only
    if (grp == 0) {
        uint4 v = *(const uint4*)(G + (size_t)w * 64 + sub * 8);
        acc[0] += bf_lo(v.x); acc[1] += bf_hi(v.x);
        acc[2] += bf_lo(v.y); acc[3] += bf_hi(v.y);
        acc[4] += bf_lo(v.z); acc[5] += bf_hi(v.z);
        acc[6] += bf_lo(v.w); acc[7] += bf_hi(v.w);
    }

    int e = 0;
    for (; e + 16 <= num; e += 16) {
        int s0 = csr[beg + e + grp];
        int s1 = csr[beg + e + 8 + grp];
        uint4 v0 = *(const uint4*)(G + (size_t)s0 * 64 + sub * 8);
        uint4 v1 = *(const uint4*)(G + (size_t)s1 * 64 + sub * 8);
        acc[0] += bf_lo(v0.x); acc[1] += bf_hi(v0.x);
        acc[2] += bf_lo(v0.y); acc[3] += bf_hi(v0.y);
        acc[4] += bf_lo(v0.z); acc[5] += bf_hi(v0.z);
        acc[6] += bf_lo(v0.w); acc[7] += bf_hi(v0.w);
        acc[0] += bf_lo(v1.x); acc[1] += bf_hi(v1.x);
        acc[2] += bf_lo(v1.y); acc[3] += bf_hi(v1.y);
        acc[4] += bf_lo(v1.z); acc[5] += bf_hi(v1.z);
        acc[6] += bf_lo(v1.w); acc[7] += bf_hi(v1.w);
    }
    if (e + 8 <= num) {
        int s0 = csr[beg + e + grp];
        uint4 v0 = *(const uint4*)(G + (size_t)s0 * 64 + sub * 8);
        acc[0] += bf_lo(v0.x); acc[1] += bf_hi(v0.x);
        acc[2] += bf_lo(v0.y); acc[3] += bf_hi(v0.y);
        acc[4] += bf_lo(v0.z); acc[5] += bf_hi(v0.z);
        acc[6] += bf_lo(v0.w); acc[7] += bf_hi(v0.w);
        e += 8;
    }
    int rem = num - e;
    if (grp < rem) {
        int s0 = csr[beg + e + grp];
        uint4 v0 = *(const uint4*)(G + (size_t)s0 * 64 + sub * 8);
        acc[0] += bf_lo(v0.x); acc[1] += bf_hi(v0.x);
        acc[2] += bf_lo(v0.y); acc[3] += bf_hi(v0.y);
        acc[4] += bf_lo(v0.z); acc[5] += bf_hi(v0.z);
        acc[6] += bf_lo(v0.w); acc[7] += bf_hi(v0.w);
    }

    // reduce across the 8 groups (lanes sharing `sub`): xor masks 8,16,32
#pragma unroll
    for (int m = 8; m <= 32; m <<= 1) {
#pragma unroll
        for (int j = 0; j < 8; ++j) acc[j] += __shfl_xor(acc[j], m, 64);
    }

    if (grp == 0) {
        float d = dinv[w];
        float4 bl0 = *(const float4*)(bias + sub * 8);
        float4 bl1 = *(const float4*)(bias + sub * 8 + 4);
        float4 o0 = make_float4(fmaf(acc[0], d, bl0.x), fmaf(acc[1], d, bl0.y),
                                fmaf(acc[2], d, bl0.z), fmaf(acc[3], d, bl0.w));
        float4 o1 = make_float4(fmaf(acc[4], d, bl1.x), fmaf(acc[5], d, bl1.y),
                                fmaf(acc[6], d, bl1.z), fmaf(acc[7], d, bl1.w));
        if (do_relu) {
            o0.x = fmaxf(o0.x, 0.f); o0.y = fmaxf(o0.y, 0.f);
            o0.z = fmaxf(o0.z, 0.f); o0.w = fmaxf(o0.w, 0.f);
            o1.x = fmaxf(o1.x, 0.f); o1.y = fmaxf(o1.y, 0.f);
            o1.z = fmaxf(o1.z, 0.f); o1.w = fmaxf(o1.w, 0.f);
        }
        *(float4*)(out + (size_t)w * 64 + sub * 8)     = o0;
        *(float4*)(out + (size_t)w * 64 + sub * 8 + 4) = o1;
    }
}

extern "C" void kernel_launch(void* const* d_in, const int* in_sizes, int n_in,
                              void* d_out, int out_size, void* d_ws, size_t ws_size,
                              hipStream_t stream) {
    const float* x  = (const float*)d_in[0];
    const int*   ei = (const int*)d_in[1];
    const float* W1 = (const float*)d_in[2];
    const float* b1 = (const float*)d_in[3];
    const float* W2 = (const float*)d_in[4];
    const float* b2 = (const float*)d_in[5];
    float* out = (float*)d_out;

    const int IN_CH = 128;
    const int N = in_sizes[0] / IN_CH;   // 100000
    const int E = in_sizes[1] / 2;       // 3200000
    const int* src = ei;
    const int* dst = ei + E;
    const int NB = (N + BKT_NODES - 1) >> BKT_SHIFT;  // 196

    char* ws = (char*)d_ws;
    size_t off = 0;
    auto take = [&](size_t bytes) -> char* {
        char* p = ws + off;
        off += (bytes + 255) & ~(size_t)255;
        return p;
    };
    int*      cnt   = (int*)take((size_t)N * 4);
    int*      offs  = (int*)take((size_t)N * 4);
    float*    dinv  = (float*)take((size_t)N * 4);
    int*      bhist = (int*)take(NBSH * 4);
    int*      boffs = (int*)take((NBSH + 1) * 4);
    int*      bcur  = (int*)take(NBSH * 4);
    int*      csr   = (int*)take((size_t)E * 4);
    ushort_t* g     = (ushort_t*)take((size_t)E * 4);       // >= N*64*2; aliases pairs
    float*    a1    = (float*)take((size_t)N * 64 * 4);
    unsigned* pairs = (unsigned*)g;  // pairs dead before gemm writes g

    const int nbC = (E + CHUNK - 1) / CHUNK;

    zero_small<<<1, 256, 0, stream>>>(bhist, bcur);
    coarse_hist<<<nbC, 256, 0, stream>>>(dst, bhist, E, NB);
    scan196<<<1, 256, 0, stream>>>(bhist, boffs, NB, E);
    bucket_bin<<<nbC, 256, 0, stream>>>(src, dst, boffs, bcur, pairs, E, NB);
    csr_sort<<<NB, 1024, MAXB * 4, stream>>>(pairs, boffs, csr, cnt, offs, dinv, N);

    // layer 1
    gemm_scale<128><<<(N + 31) / 32, 256, 0, stream>>>(x, W1, dinv, g, N);
    aggregate<<<(N + 3) / 4, 256, 0, stream>>>(g, offs, cnt, csr, dinv, b1, a1, N, 1);
    // layer 2
    gemm_scale<64><<<(N + 31) / 32, 256, 0, stream>>>(a1, W2, dinv, g, N);
    aggregate<<<(N + 3) / 4, 256, 0, stream>>>(g, offs, cnt, csr, dinv, b2, out, N, 0);
}